// Round 2
// baseline (1442.932 us; speedup 1.0000x reference)
//
#include <hip/hip_runtime.h>
#include <math.h>

#define N_ROWS 12544   // 16*28*28
#define C_DIM  1536
#define M_ROWS 16384
#define BATCH  16

typedef __bf16 bf16;
typedef __bf16 bf16x8 __attribute__((ext_vector_type(8)));
typedef float  f32x4  __attribute__((ext_vector_type(4)));

// order-preserving float->uint key for atomicMin
__device__ __forceinline__ unsigned fkey(float f) {
  unsigned u = __float_as_uint(f);
  return (u & 0x80000000u) ? ~u : (u | 0x80000000u);
}
__device__ __forceinline__ float funkey(unsigned k) {
  unsigned u = (k & 0x80000000u) ? (k ^ 0x80000000u) : ~k;
  return __uint_as_float(u);
}

__device__ __forceinline__ void gl_lds16(const void* g, void* l) {
  __builtin_amdgcn_global_load_lds(
      (__attribute__((address_space(1))) void*)(g),
      (__attribute__((address_space(3))) void*)(l), 16, 0, 0);
}

// ---------------- Kernel A: build bf16 feature rows + x_sq ----------------
// One block per (b, y) row: 28 output pixels x 1536 channels.
// Lane owns a channel -> contiguous spatial reads; coalesced c-writes per x.
__global__ __launch_bounds__(512) void prep_feats(
    const float* __restrict__ feat2, const float* __restrict__ feat3,
    bf16* __restrict__ feats, float* __restrict__ xsq) {
  const int blk = blockIdx.x;            // 0..447 = b*28 + y
  const int b = blk / 28, y = blk % 28;
  const int t = threadIdx.x;             // 0..511
  const int lane = t & 63, wave = t >> 6;

  __shared__ float wxs[28];
  __shared__ int   x0s[28], x1s[28];
  __shared__ float sred[8 * 28];
  if (t < 28) {
    const float sx = 0.5f * t - 0.25f;
    const int x0 = (int)floorf(sx);
    wxs[t] = sx - (float)x0;
    x0s[t] = max(x0, 0);
    x1s[t] = min(x0 + 1, 13);
  }
  __syncthreads();

  const float sy = 0.5f * y - 0.25f;
  const int y0 = (int)floorf(sy);
  const float fy = sy - (float)y0;
  const int y0c = max(y0, 0), y1c = min(y0 + 1, 13);

  float sacc[28];
#pragma unroll
  for (int x = 0; x < 28; x++) sacc[x] = 0.f;

  const size_t nrow0 = (size_t)blk * 28;
  for (int iter = 0; iter < 3; iter++) {
    const int c = t + iter * 512;
    bf16* dst = feats + nrow0 * C_DIM + c;
    if (c < 512) {
      const float* src = feat2 + (((size_t)b * 512 + c) * 28 + y) * 28;
#pragma unroll
      for (int x = 0; x < 28; x++) {
        bf16 hb = (bf16)src[x];
        dst[(size_t)x * C_DIM] = hb;
        float vb = (float)hb;
        sacc[x] += vb * vb;
      }
    } else {
      const int c3 = c - 512;
      const float* f3 = feat3 + ((size_t)b * 1024 + c3) * 196;
      const float* r0 = f3 + y0c * 14;
      const float* r1 = f3 + y1c * 14;
#pragma unroll
      for (int x = 0; x < 28; x++) {
        const float fx = wxs[x];
        const int xa = x0s[x], xb = x1s[x];
        const float w00 = (1.f-fy)*(1.f-fx), w01 = (1.f-fy)*fx;
        const float w10 = fy*(1.f-fx),       w11 = fy*fx;
        float v = w00*r0[xa] + w01*r0[xb] + w10*r1[xa] + w11*r1[xb];
        bf16 hb = (bf16)v;
        dst[(size_t)x * C_DIM] = hb;
        float vb = (float)hb;
        sacc[x] += vb * vb;
      }
    }
  }
  // reduce sacc[x] across 512 threads
#pragma unroll
  for (int x = 0; x < 28; x++) {
    float v = sacc[x];
    for (int off = 32; off > 0; off >>= 1) v += __shfl_down(v, off, 64);
    if (lane == 0) sred[wave * 28 + x] = v;
  }
  __syncthreads();
  if (t < 28) {
    float s = 0.f;
#pragma unroll
    for (int w = 0; w < 8; w++) s += sred[w * 28 + t];
    xsq[nrow0 + t] = s;
  }
}

// ---------------- Kernel B: bf16 memory bank + m_sq (float4 loads) --------
__global__ __launch_bounds__(384) void prep_mb(
    const float* __restrict__ mb, bf16* __restrict__ mbb,
    float* __restrict__ msq) {
  const int j = blockIdx.x, t = threadIdx.x;   // 384 threads * 4 floats = 1536
  const float4 v = *(const float4*)(mb + (size_t)j * C_DIM + t * 4);
  bf16 h0 = (bf16)v.x, h1 = (bf16)v.y, h2 = (bf16)v.z, h3 = (bf16)v.w;
  bf16* out = mbb + (size_t)j * C_DIM + t * 4;
  out[0] = h0; out[1] = h1; out[2] = h2; out[3] = h3;
  float ssq = (float)h0*(float)h0 + (float)h1*(float)h1
            + (float)h2*(float)h2 + (float)h3*(float)h3;
  __shared__ float sred[6];
  for (int off = 32; off > 0; off >>= 1) ssq += __shfl_down(ssq, off, 64);
  if ((t & 63) == 0) sred[t >> 6] = ssq;
  __syncthreads();
  if (t == 0) {
    float s = 0.f;
#pragma unroll
    for (int w = 0; w < 6; w++) s += sred[w];
    msq[j] = s;
  }
}

// ---------------- init min buffer ----------------
__global__ void init_min(unsigned* __restrict__ dmin) {
  int i = blockIdx.x * 256 + threadIdx.x;
  if (i < N_ROWS) dmin[i] = 0xFFFFFFFFu;
}

// ---------------- Kernel C: bf16 MFMA GEMM + fused min over M ----------------
// 128x128 tile, BK=32. LDS in FRAGMENT ORDER: byte addr = rb*1024 + chunk*256
// + row16*16  (rb = row>>4, chunk = k>>3). Fragment ds_read_b128 per lane is
// base + lane*16 -> contiguous 1KB, zero bank conflicts.
__global__ void gemm_min(const bf16* __restrict__ X, const bf16* __restrict__ Mb,
                         const float* __restrict__ msq,
                         unsigned* __restrict__ dmin) {
  __shared__ bf16 As[128 * 32];
  __shared__ bf16 Bs[128 * 32];
  __shared__ unsigned smin[128];
  const int t = threadIdx.x;
  const int mtile = blockIdx.x;   // 0..127 over M
  const int ntile = blockIdx.y;   // 0..97  over N
  const int lane = t & 63, wave = t >> 6;
  const int wm = wave >> 1, wn = wave & 1;
  if (t < 128) smin[t] = 0xFFFFFFFFu;

  const int row0 = ntile * 128;
  const int col0 = mtile * 128;
  // staging: thread t fills LDS bytes [t*16, t*16+16) = (rb=t>>6, ch=(t>>4)&3,
  // r16=t&15) -> global row (t>>6)*16+(t&15), k-chunk (t>>4)&3
  const int s_row = ((t >> 6) << 4) + (t & 15);
  const int s_ch  = (t >> 4) & 3;
  const bf16* ga = X  + (size_t)(row0 + s_row) * C_DIM + s_ch * 8;
  const bf16* gb = Mb + (size_t)(col0 + s_row) * C_DIM + s_ch * 8;
  bf16* la = As + t * 8;
  bf16* lb = Bs + t * 8;

  f32x4 acc[4][4];
  const f32x4 zero = {0.f, 0.f, 0.f, 0.f};
#pragma unroll
  for (int mi = 0; mi < 4; mi++)
#pragma unroll
    for (int ni = 0; ni < 4; ni++) acc[mi][ni] = zero;

  const int quad = lane >> 4, l16 = lane & 15;
  // fragment base: rb = wm*4 + mi ; elem offset = rb*512 + quad*128 + l16*8
  const bf16* arow = As + wm * 2048 + quad * 128 + l16 * 8;
  const bf16* brow = Bs + wn * 2048 + quad * 128 + l16 * 8;

  for (int k0 = 0; k0 < C_DIM; k0 += 32) {
    __syncthreads();
    gl_lds16(ga + k0,               la);
    gl_lds16(ga + 64 * C_DIM + k0,  la + 2048);   // rows 64..127 -> rb 4..7
    gl_lds16(gb + k0,               lb);
    gl_lds16(gb + 64 * C_DIM + k0,  lb + 2048);
    __syncthreads();
    bf16x8 afrag[4], bfrag[4];
#pragma unroll
    for (int mi = 0; mi < 4; mi++)
      afrag[mi] = *(const bf16x8*)(arow + mi * 512);
#pragma unroll
    for (int ni = 0; ni < 4; ni++)
      bfrag[ni] = *(const bf16x8*)(brow + ni * 512);
#pragma unroll
    for (int mi = 0; mi < 4; mi++)
#pragma unroll
      for (int ni = 0; ni < 4; ni++)
        acc[mi][ni] = __builtin_amdgcn_mfma_f32_16x16x32_bf16(
            afrag[mi], bfrag[ni], acc[mi][ni], 0, 0, 0);
  }

  // epilogue: v = m_sq[j] - 2*dot ; min over this block's 128-col slab
  float msql[4];
#pragma unroll
  for (int ni = 0; ni < 4; ni++)
    msql[ni] = msq[col0 + wn * 64 + ni * 16 + l16];

#pragma unroll
  for (int mi = 0; mi < 4; mi++) {
#pragma unroll
    for (int r = 0; r < 4; r++) {
      float v = msql[0] - 2.f * acc[mi][0][r];
#pragma unroll
      for (int ni = 1; ni < 4; ni++)
        v = fminf(v, msql[ni] - 2.f * acc[mi][ni][r]);
      v = fminf(v, __shfl_xor(v, 1, 64));
      v = fminf(v, __shfl_xor(v, 2, 64));
      v = fminf(v, __shfl_xor(v, 4, 64));
      v = fminf(v, __shfl_xor(v, 8, 64));
      if (l16 == 0) {
        int lrow = wm * 64 + mi * 16 + quad * 4 + r;  // C/D: row = quad*4 + reg
        atomicMin(&smin[lrow], fkey(v));
      }
    }
  }
  __syncthreads();
  if (t < 128) atomicMin(&dmin[row0 + t], smin[t]);
}

// ---------------- Kernel D: sqrt + 28->224 bilinear + per-image max ----------
__global__ void finalize(const unsigned* __restrict__ dmin,
                         const float* __restrict__ xsq,
                         float* __restrict__ out) {
  const int b = blockIdx.x, t = threadIdx.x;
  __shared__ float smap[784];
  __shared__ float sred[4];
  for (int i = t; i < 784; i += 256) {
    float d2 = xsq[b * 784 + i] + funkey(dmin[b * 784 + i]);
    smap[i] = sqrtf(fmaxf(d2, 0.f));
  }
  __syncthreads();
  float* omap = out + (size_t)b * 50176;
  float tmax = -1e30f;
  for (int p = t; p < 50176; p += 256) {
    const int Y = p / 224, Xp = p % 224;
    const float sy = Y * 0.125f - 0.4375f;   // (dst+0.5)/8 - 0.5
    const float sx = Xp * 0.125f - 0.4375f;
    const int y0 = (int)floorf(sy); const float fy = sy - (float)y0;
    const int x0 = (int)floorf(sx); const float fx = sx - (float)x0;
    const int y0c = max(y0, 0), y1c = min(y0 + 1, 27);
    const int x0c = max(x0, 0), x1c = min(x0 + 1, 27);
    float v = (1.f-fy)*((1.f-fx)*smap[y0c*28+x0c] + fx*smap[y0c*28+x1c])
            +      fy *((1.f-fx)*smap[y1c*28+x0c] + fx*smap[y1c*28+x1c]);
    omap[p] = v;
    tmax = fmaxf(tmax, v);
  }
  for (int off = 32; off > 0; off >>= 1)
    tmax = fmaxf(tmax, __shfl_down(tmax, off, 64));
  if ((t & 63) == 0) sred[t >> 6] = tmax;
  __syncthreads();
  if (t == 0)
    out[802816 + b] = fmaxf(fmaxf(sred[0], sred[1]), fmaxf(sred[2], sred[3]));
}

extern "C" void kernel_launch(void* const* d_in, const int* in_sizes, int n_in,
                              void* d_out, int out_size, void* d_ws, size_t ws_size,
                              hipStream_t stream) {
  const float* feat2 = (const float*)d_in[0];  // [16,512,28,28]
  const float* feat3 = (const float*)d_in[1];  // [16,1024,14,14]
  const float* mb    = (const float*)d_in[2];  // [16384,1536]
  char* ws = (char*)d_ws;
  bf16*     feats = (bf16*)ws;                         // 12544*1536*2
  bf16*     mbb   = (bf16*)(ws + 38535168);            // 16384*1536*2
  float*    xsq   = (float*)(ws + 88866816);           // 12544*4
  float*    msq   = (float*)(ws + 88916992);           // 16384*4
  unsigned* dmin  = (unsigned*)(ws + 88982528);        // 12544*4
  float* out = (float*)d_out;

  prep_feats<<<448, 512, 0, stream>>>(feat2, feat3, feats, xsq);
  prep_mb<<<M_ROWS, 384, 0, stream>>>(mb, mbb, msq);
  init_min<<<(N_ROWS + 255) / 256, 256, 0, stream>>>(dmin);
  gemm_min<<<dim3(128, 98), 256, 0, stream>>>(feats, mbb, msq, dmin);
  finalize<<<BATCH, 256, 0, stream>>>(dmin, xsq, out);
}

// Round 3
// 1012.039 us; speedup vs baseline: 1.4258x; 1.4258x over previous
//
#include <hip/hip_runtime.h>
#include <math.h>

#define N_ROWS 12544   // 16*28*28
#define C_DIM  1536
#define M_ROWS 16384
#define BATCH  16

typedef __bf16 bf16;
typedef __bf16 bf16x8 __attribute__((ext_vector_type(8)));
typedef float  f32x4  __attribute__((ext_vector_type(4)));

// order-preserving float->uint key for atomicMin
__device__ __forceinline__ unsigned fkey(float f) {
  unsigned u = __float_as_uint(f);
  return (u & 0x80000000u) ? ~u : (u | 0x80000000u);
}
__device__ __forceinline__ float funkey(unsigned k) {
  unsigned u = (k & 0x80000000u) ? (k ^ 0x80000000u) : ~k;
  return __uint_as_float(u);
}

__device__ __forceinline__ void gl_lds16(const void* g, void* l) {
  __builtin_amdgcn_global_load_lds(
      (__attribute__((address_space(1))) void*)(g),
      (__attribute__((address_space(3))) void*)(l), 16, 0, 0);
}

// ---------------- Kernel A: build bf16 feature rows + x_sq (R0 form) -------
__global__ void prep_feats(const float* __restrict__ feat2,
                           const float* __restrict__ feat3,
                           bf16* __restrict__ feats,
                           float* __restrict__ xsq) {
  const int n = blockIdx.x;
  const int t = threadIdx.x;
  const int b = n / 784;
  const int rem = n % 784;
  const int y = rem / 28, x = rem % 28;
  const float sy = 0.5f * y - 0.25f;
  const float sx = 0.5f * x - 0.25f;
  const int y0 = (int)floorf(sy); const float fy = sy - (float)y0;
  const int x0 = (int)floorf(sx); const float fx = sx - (float)x0;
  const int y0c = max(y0, 0), y1c = min(y0 + 1, 13);
  const int x0c = max(x0, 0), x1c = min(x0 + 1, 13);
  const float w00 = (1.f-fy)*(1.f-fx), w01 = (1.f-fy)*fx;
  const float w10 = fy*(1.f-fx),       w11 = fy*fx;

  float ssq = 0.f;
  bf16* orow = feats + (size_t)n * C_DIM;
  for (int c = t; c < C_DIM; c += 256) {
    float v;
    if (c < 512) {
      v = feat2[(((size_t)b * 512 + c) * 28 + y) * 28 + x];
    } else {
      const float* f3 = feat3 + ((size_t)b * 1024 + (c - 512)) * 196;
      v = w00 * f3[y0c*14 + x0c] + w01 * f3[y0c*14 + x1c]
        + w10 * f3[y1c*14 + x0c] + w11 * f3[y1c*14 + x1c];
    }
    bf16 hb = (bf16)v;
    orow[c] = hb;
    float vb = (float)hb;
    ssq += vb * vb;
  }
  __shared__ float sred[4];
  for (int off = 32; off > 0; off >>= 1) ssq += __shfl_down(ssq, off, 64);
  if ((t & 63) == 0) sred[t >> 6] = ssq;
  __syncthreads();
  if (t == 0) xsq[n] = sred[0] + sred[1] + sred[2] + sred[3];
}

// ---------------- Kernel B: bf16 memory bank + m_sq (float4 loads) --------
__global__ __launch_bounds__(384) void prep_mb(
    const float* __restrict__ mb, bf16* __restrict__ mbb,
    float* __restrict__ msq) {
  const int j = blockIdx.x, t = threadIdx.x;   // 384 threads * 4 floats = 1536
  const float4 v = *(const float4*)(mb + (size_t)j * C_DIM + t * 4);
  bf16 h0 = (bf16)v.x, h1 = (bf16)v.y, h2 = (bf16)v.z, h3 = (bf16)v.w;
  bf16* out = mbb + (size_t)j * C_DIM + t * 4;
  out[0] = h0; out[1] = h1; out[2] = h2; out[3] = h3;
  float ssq = (float)h0*(float)h0 + (float)h1*(float)h1
            + (float)h2*(float)h2 + (float)h3*(float)h3;
  __shared__ float sred[6];
  for (int off = 32; off > 0; off >>= 1) ssq += __shfl_down(ssq, off, 64);
  if ((t & 63) == 0) sred[t >> 6] = ssq;
  __syncthreads();
  if (t == 0) {
    float s = 0.f;
#pragma unroll
    for (int w = 0; w < 6; w++) s += sred[w];
    msq[j] = s;
  }
}

// ---------------- init min buffer + score slots ----------------
__global__ void init_min(unsigned* __restrict__ dmin,
                         unsigned* __restrict__ score) {
  int i = blockIdx.x * 256 + threadIdx.x;
  if (i < N_ROWS) dmin[i] = 0xFFFFFFFFu;
  if (i < BATCH) score[i] = 0u;   // 0.0f; anomaly values are >= 0
}

// ---------------- Kernel C: bf16 MFMA GEMM + fused min over M ----------------
// 128x128 tile, BK=32. XOR-swizzled LDS: byte addr = row*64 + slot*16, slot
// holds global chunk  ch = slot ^ ((row>>1)&3).
//  - staging (global_load_lds, lane*16 dest): 4-lane groups read a permuted
//    contiguous 64B segment -> coalescing preserved
//  - fragment ds_read_b128: bank load perfectly uniform (<=2-way, free)
__global__ void gemm_min(const bf16* __restrict__ X, const bf16* __restrict__ Mb,
                         const float* __restrict__ msq,
                         unsigned* __restrict__ dmin) {
  __shared__ bf16 As[128 * 32];
  __shared__ bf16 Bs[128 * 32];
  __shared__ unsigned smin[128];
  const int t = threadIdx.x;
  const int mtile = blockIdx.x;   // 0..127 over M
  const int ntile = blockIdx.y;   // 0..97  over N
  const int lane = t & 63, wave = t >> 6;
  const int wm = wave >> 1, wn = wave & 1;
  if (t < 128) smin[t] = 0xFFFFFFFFu;

  const int row0 = ntile * 128;
  const int col0 = mtile * 128;
  // staging: thread t fills LDS slot (row=t>>2, slot=t&3); global chunk
  // ch = (t&3) ^ ((t>>3)&3)   [= slot ^ ((row>>1)&3)]
  const int s_row = t >> 2;
  const int s_ch  = (t & 3) ^ ((t >> 3) & 3);
  const bf16* ga = X  + (size_t)(row0 + s_row) * C_DIM + s_ch * 8;
  const bf16* gb = Mb + (size_t)(col0 + s_row) * C_DIM + s_ch * 8;
  bf16* la = As + t * 8;
  bf16* lb = Bs + t * 8;

  f32x4 acc[4][4];
  const f32x4 zero = {0.f, 0.f, 0.f, 0.f};
#pragma unroll
  for (int mi = 0; mi < 4; mi++)
#pragma unroll
    for (int ni = 0; ni < 4; ni++) acc[mi][ni] = zero;

  const int quad = lane >> 4, l16 = lane & 15;
  // fragment base for (row = base16 + l16, chunk = quad):
  // elem off = row*32 + (quad ^ ((l16>>1)&3))*8   (swizzle indep. of base16)
  const int fswz = (quad ^ ((l16 >> 1) & 3)) * 8;
  const bf16* arow = As + (wm * 64 + l16) * 32 + fswz;
  const bf16* brow = Bs + (wn * 64 + l16) * 32 + fswz;

  for (int k0 = 0; k0 < C_DIM; k0 += 32) {
    __syncthreads();
    gl_lds16(ga + k0,               la);
    gl_lds16(ga + 64 * C_DIM + k0,  la + 2048);   // rows 64..127
    gl_lds16(gb + k0,               lb);
    gl_lds16(gb + 64 * C_DIM + k0,  lb + 2048);
    __syncthreads();
    bf16x8 afrag[4], bfrag[4];
#pragma unroll
    for (int mi = 0; mi < 4; mi++)
      afrag[mi] = *(const bf16x8*)(arow + mi * 512);   // +16 rows
#pragma unroll
    for (int ni = 0; ni < 4; ni++)
      bfrag[ni] = *(const bf16x8*)(brow + ni * 512);
#pragma unroll
    for (int mi = 0; mi < 4; mi++)
#pragma unroll
      for (int ni = 0; ni < 4; ni++)
        acc[mi][ni] = __builtin_amdgcn_mfma_f32_16x16x32_bf16(
            afrag[mi], bfrag[ni], acc[mi][ni], 0, 0, 0);
  }

  // epilogue: v = m_sq[j] - 2*dot ; min over this block's 128-col slab
  float msql[4];
#pragma unroll
  for (int ni = 0; ni < 4; ni++)
    msql[ni] = msq[col0 + wn * 64 + ni * 16 + l16];

#pragma unroll
  for (int mi = 0; mi < 4; mi++) {
#pragma unroll
    for (int r = 0; r < 4; r++) {
      float v = msql[0] - 2.f * acc[mi][0][r];
#pragma unroll
      for (int ni = 1; ni < 4; ni++)
        v = fminf(v, msql[ni] - 2.f * acc[mi][ni][r]);
      v = fminf(v, __shfl_xor(v, 1, 64));
      v = fminf(v, __shfl_xor(v, 2, 64));
      v = fminf(v, __shfl_xor(v, 4, 64));
      v = fminf(v, __shfl_xor(v, 8, 64));
      if (l16 == 0) {
        int lrow = wm * 64 + mi * 16 + quad * 4 + r;  // C/D: row = quad*4 + reg
        atomicMin(&smin[lrow], fkey(v));
      }
    }
  }
  __syncthreads();
  if (t < 128) atomicMin(&dmin[row0 + t], smin[t]);
}

// ------- Kernel D: sqrt + 28->224 bilinear + per-image max (128 blocks) -----
__global__ void finalize(const unsigned* __restrict__ dmin,
                         const float* __restrict__ xsq,
                         float* __restrict__ out) {
  const int b = blockIdx.x, slice = blockIdx.y, t = threadIdx.x;
  __shared__ float smap[784];
  __shared__ float sred[4];
  for (int i = t; i < 784; i += 256) {
    float d2 = xsq[b * 784 + i] + funkey(dmin[b * 784 + i]);
    smap[i] = sqrtf(fmaxf(d2, 0.f));
  }
  __syncthreads();
  float* omap = out + (size_t)b * 50176;
  float tmax = 0.f;
  const int p0 = slice * 6272;           // 28 output rows per slice
  for (int p = p0 + t; p < p0 + 6272; p += 256) {
    const int Y = p / 224, Xp = p % 224;
    const float sy = Y * 0.125f - 0.4375f;   // (dst+0.5)/8 - 0.5
    const float sx = Xp * 0.125f - 0.4375f;
    const int y0 = (int)floorf(sy); const float fy = sy - (float)y0;
    const int x0 = (int)floorf(sx); const float fx = sx - (float)x0;
    const int y0c = max(y0, 0), y1c = min(y0 + 1, 27);
    const int x0c = max(x0, 0), x1c = min(x0 + 1, 27);
    float v = (1.f-fy)*((1.f-fx)*smap[y0c*28+x0c] + fx*smap[y0c*28+x1c])
            +      fy *((1.f-fx)*smap[y1c*28+x0c] + fx*smap[y1c*28+x1c]);
    omap[p] = v;
    tmax = fmaxf(tmax, v);
  }
  for (int off = 32; off > 0; off >>= 1)
    tmax = fmaxf(tmax, __shfl_down(tmax, off, 64));
  if ((t & 63) == 0) sred[t >> 6] = tmax;
  __syncthreads();
  if (t == 0) {
    float m = fmaxf(fmaxf(sred[0], sred[1]), fmaxf(sred[2], sred[3]));
    // values >= 0: uint bit-pattern order == float order
    atomicMax((unsigned*)(out + 802816 + b), __float_as_uint(m));
  }
}

extern "C" void kernel_launch(void* const* d_in, const int* in_sizes, int n_in,
                              void* d_out, int out_size, void* d_ws, size_t ws_size,
                              hipStream_t stream) {
  const float* feat2 = (const float*)d_in[0];  // [16,512,28,28]
  const float* feat3 = (const float*)d_in[1];  // [16,1024,14,14]
  const float* mb    = (const float*)d_in[2];  // [16384,1536]
  char* ws = (char*)d_ws;
  bf16*     feats = (bf16*)ws;                         // 12544*1536*2
  bf16*     mbb   = (bf16*)(ws + 38535168);            // 16384*1536*2
  float*    xsq   = (float*)(ws + 88866816);           // 12544*4
  float*    msq   = (float*)(ws + 88916992);           // 16384*4
  unsigned* dmin  = (unsigned*)(ws + 88982528);        // 12544*4
  float* out = (float*)d_out;

  prep_feats<<<N_ROWS, 256, 0, stream>>>(feat2, feat3, feats, xsq);
  prep_mb<<<M_ROWS, 384, 0, stream>>>(mb, mbb, msq);
  init_min<<<(N_ROWS + 255) / 256, 256, 0, stream>>>(
      dmin, (unsigned*)(out + 802816));
  gemm_min<<<dim3(128, 98), 256, 0, stream>>>(feats, mbb, msq, dmin);
  finalize<<<dim3(BATCH, 8), 256, 0, stream>>>(dmin, xsq, out);
}